// Round 1
// baseline (296.438 us; speedup 1.0000x reference)
//
#include <hip/hip_runtime.h>
#include <hip/hip_fp16.h>

// Problem constants
#define BATCH 4096
#define HH 32
#define WW 32
#define KPROP 20
#define NACT 4
#define DIN 3072   // H*W*3
#define DPHI 2048  // 2*H*W
#define HWC 1024   // H*W

typedef _Float16 half8 __attribute__((ext_vector_type(8)));
typedef float f32x4 __attribute__((ext_vector_type(4)));

// ---------------- Kernel A: phi = sigmoid(obs @ Phi_w + Phi_b) ----------------
// M=4096, N=2048, K=3072. 128x128 tile, BK=32, 256 threads (4 waves, 2x2 of 64x64).
// LDS fragment-major layout: As2[kq][row][8] so b128 fragment reads are conflict-free.
#define BM 128
#define BN 128
#define BK 32

__global__ __launch_bounds__(256) void gemm_phi_kernel(
    const float* __restrict__ A,    // (4096, 3072)
    const float* __restrict__ Bw,   // (3072, 2048)
    const float* __restrict__ bias, // (2048,)
    float* __restrict__ phi)        // (4096, 2048)
{
    __shared__ _Float16 As2[4 * BM * 8];  // [kq][m][j]  8 KB
    __shared__ _Float16 Bs2[4 * BN * 8];  // [kq][n][j]  8 KB

    const int tid  = threadIdx.x;
    const int wid  = tid >> 6;
    const int lane = tid & 63;
    const int m0 = blockIdx.y * BM;
    const int n0 = blockIdx.x * BN;
    const int wm = (wid >> 1) * 64;
    const int wn = (wid & 1) * 64;
    const int lm = lane & 15;
    const int kq = lane >> 4;  // 0..3

    f32x4 acc[4][4] = {};

    // A staging: thread handles rows (tid>>3)+32s, k-chunk (tid&7)*4
    const int ar = tid >> 3;
    const int ak = (tid & 7) * 4;
    // B staging: thread handles n = tid&127, k pairs in half (tid>>7)
    const int bn = tid & 127;
    const int bh = (tid >> 7) * 16;

    for (int k0 = 0; k0 < DIN; k0 += BK) {
        // ---- stage A (fp32 -> f16) ----
        #pragma unroll
        for (int s = 0; s < 4; s++) {
            const int row = ar + 32 * s;
            const float4 v = *(const float4*)(A + (size_t)(m0 + row) * DIN + k0 + ak);
            _Float16* dst = As2 + ((ak >> 3) * BM + row) * 8 + (ak & 7);
            dst[0] = (_Float16)v.x; dst[1] = (_Float16)v.y;
            dst[2] = (_Float16)v.z; dst[3] = (_Float16)v.w;
        }
        // ---- stage B (fp32 -> f16), gather 2 consecutive k per n ----
        #pragma unroll
        for (int s = 0; s < 8; s++) {
            const int k = bh + 2 * s;
            const float v0 = Bw[(size_t)(k0 + k) * DPHI + n0 + bn];
            const float v1 = Bw[(size_t)(k0 + k + 1) * DPHI + n0 + bn];
            _Float16* dst = Bs2 + ((k >> 3) * BN + bn) * 8 + (k & 7);
            dst[0] = (_Float16)v0; dst[1] = (_Float16)v1;
        }
        __syncthreads();

        half8 afrag[4], bfrag[4];
        #pragma unroll
        for (int mt = 0; mt < 4; mt++)
            afrag[mt] = *(const half8*)(As2 + (kq * BM + wm + mt * 16 + lm) * 8);
        #pragma unroll
        for (int nt = 0; nt < 4; nt++)
            bfrag[nt] = *(const half8*)(Bs2 + (kq * BN + wn + nt * 16 + lm) * 8);

        #pragma unroll
        for (int mt = 0; mt < 4; mt++)
            #pragma unroll
            for (int nt = 0; nt < 4; nt++)
                acc[mt][nt] = __builtin_amdgcn_mfma_f32_16x16x32_f16(
                    afrag[mt], bfrag[nt], acc[mt][nt], 0, 0, 0);
        __syncthreads();
    }

    // ---- epilogue: bias + sigmoid, fp32 store ----
    #pragma unroll
    for (int nt = 0; nt < 4; nt++) {
        const int col = n0 + wn + nt * 16 + lm;
        const float bcol = bias[col];
        #pragma unroll
        for (int mt = 0; mt < 4; mt++) {
            #pragma unroll
            for (int r = 0; r < 4; r++) {
                const int row = m0 + wm + mt * 16 + kq * 4 + r;
                const float v = acc[mt][nt][r] + bcol;
                phi[(size_t)row * DPHI + col] = 1.0f / (1.0f + __expf(-v));
            }
        }
    }
}

// -------- Kernel B: value propagation + agent gather + 36->16->4 MLP --------
__global__ __launch_bounds__(256) void vprop_head_kernel(
    const float* __restrict__ phi,  // (4096, 2048) interleaved (r,p)
    const float* __restrict__ obs,  // (4096, 3072)
    const float* __restrict__ L1w,  // (36,16)
    const float* __restrict__ L1b,  // (16,)
    const float* __restrict__ L2w,  // (16,4)
    const float* __restrict__ L2b,  // (4,)
    float* __restrict__ out)        // (4096, 4)
{
    __shared__ float r[HWC], p[HWC], V0[HWC], V1[HWC];
    __shared__ float sel[36], hbuf[16];
    __shared__ int agent;

    const int b = blockIdx.x;
    const int tid = threadIdx.x;

    if (tid == 0) agent = 0;
    #pragma unroll
    for (int q = 0; q < 4; q++) {
        const int c = tid + 256 * q;
        const float2 v = *(const float2*)(phi + (size_t)b * DPHI + 2 * c);
        r[c] = v.x; p[c] = v.y; V0[c] = v.x;
    }
    __syncthreads();

    // one-hot agent scan (exactly one 1.0 in channel 1)
    #pragma unroll
    for (int q = 0; q < 4; q++) {
        const int c = tid + 256 * q;
        if (obs[(size_t)b * DIN + 3 * c + 1] > 0.5f) agent = c;
    }

    float* Vold = V0;
    float* Vnew = V1;
    for (int it = 0; it < KPROP; it++) {
        #pragma unroll
        for (int q = 0; q < 4; q++) {
            const int c = tid + 256 * q;
            const int i = c >> 5, j = c & 31;
            const float up    = (i > 0)  ? Vold[c - 32] : 0.0f;
            const float down  = (i < 31) ? Vold[c + 32] : 0.0f;
            const float left  = (j > 0)  ? Vold[c - 1]  : 0.0f;
            const float right = (j < 31) ? Vold[c + 1]  : 0.0f;
            const float nbr = fmaxf(fmaxf(up, down), fmaxf(left, right));
            const float rv = r[c];
            Vnew[c] = fmaxf(Vold[c], rv + p[c] * (nbr - rv));
        }
        __syncthreads();
        float* t = Vold; Vold = Vnew; Vnew = t;
    }

    // gather 3x3x4 neighborhood around agent
    const int aidx = agent;
    const int pi = aidx >> 5, pj = aidx & 31;
    if (tid < 36) {
        const int cell = tid >> 2;   // 0..8
        const int ch = tid & 3;      // 0..3
        const int i = pi + cell / 3 - 1;
        const int j = pj + cell % 3 - 1;
        float v = 0.0f;
        if (i >= 0 && i < HH && j >= 0 && j < WW) {
            const int c = i * WW + j;
            v = (ch < 3) ? obs[(size_t)b * DIN + 3 * c + ch] : Vold[c];
        }
        sel[tid] = v;
    }
    __syncthreads();

    if (tid < 16) {
        float h = L1b[tid];
        #pragma unroll
        for (int k = 0; k < 36; k++) h += sel[k] * L1w[k * 16 + tid];
        hbuf[tid] = fmaxf(h, 0.0f);
    }
    __syncthreads();

    if (tid < 4) {
        float o = L2b[tid];
        #pragma unroll
        for (int t = 0; t < 16; t++) o += hbuf[t] * L2w[t * 4 + tid];
        out[(size_t)b * NACT + tid] = o;
    }
}

extern "C" void kernel_launch(void* const* d_in, const int* in_sizes, int n_in,
                              void* d_out, int out_size, void* d_ws, size_t ws_size,
                              hipStream_t stream) {
    const float* obs   = (const float*)d_in[0];
    const float* Phi_w = (const float*)d_in[1];
    const float* Phi_b = (const float*)d_in[2];
    const float* L1w   = (const float*)d_in[3];
    const float* L1b   = (const float*)d_in[4];
    const float* L2w   = (const float*)d_in[5];
    const float* L2b   = (const float*)d_in[6];
    float* out = (float*)d_out;
    float* phi = (float*)d_ws;  // 4096*2048 fp32 = 33.6 MB

    dim3 g1(DPHI / BN, BATCH / BM);  // (16, 32) = 512 blocks
    gemm_phi_kernel<<<g1, 256, 0, stream>>>(obs, Phi_w, Phi_b, phi);
    vprop_head_kernel<<<BATCH, 256, 0, stream>>>(phi, obs, L1w, L1b, L2w, L2b, out);
}

// Round 2
// 182.215 us; speedup vs baseline: 1.6269x; 1.6269x over previous
//
#include <hip/hip_runtime.h>
#include <hip/hip_fp16.h>

#define BATCH 4096
#define HH 32
#define WW 32
#define KPROP 20
#define NACT 4
#define DIN 3072   // H*W*3
#define DPHI 2048  // 2*H*W
#define HWC 1024   // H*W
#define KC 1024    // compacted K (walls only)

typedef _Float16 h8_t __attribute__((ext_vector_type(8)));
typedef _Float16 h4_t __attribute__((ext_vector_type(4)));
typedef float f32x4 __attribute__((ext_vector_type(4)));

__device__ inline void load_lds16(const _Float16* g, _Float16* l) {
    __builtin_amdgcn_global_load_lds(
        (const __attribute__((address_space(1))) void*)g,
        (__attribute__((address_space(3))) void*)l, 16, 0, 0);
}

__device__ inline float sigmoidf(float x) { return 1.0f / (1.0f + __expf(-x)); }

// ---------------- P1: compact walls to f16, extract agent/goal indices ----------------
// thread handles 4 cells (12 consecutive floats = 3 float4 loads, fully coalesced)
__global__ __launch_bounds__(256) void prep_kernel(
    const float* __restrict__ obs,  // (4096, 3072)
    _Float16* __restrict__ W16,     // (4096, 1024)
    int* __restrict__ aidx, int* __restrict__ gidx)
{
    const int t = blockIdx.x * 256 + threadIdx.x;   // 0 .. 1048575
    const int b = t >> 8;
    const int c0 = (t & 255) * 4;
    const float* src = obs + (size_t)b * DIN + 3 * c0;
    const float4 f0 = *(const float4*)(src);
    const float4 f1 = *(const float4*)(src + 4);
    const float4 f2 = *(const float4*)(src + 8);
    // cells c0+d: wall f[3d], agent f[3d+1], goal f[3d+2]
    h4_t w;
    w[0] = (_Float16)f0.x; w[1] = (_Float16)f0.w;
    w[2] = (_Float16)f1.z; w[3] = (_Float16)f2.y;
    *(h4_t*)(W16 + (size_t)b * KC + c0) = w;
    if (f0.y > 0.5f) aidx[b] = c0;
    if (f1.x > 0.5f) aidx[b] = c0 + 1;
    if (f1.w > 0.5f) aidx[b] = c0 + 2;
    if (f2.z > 0.5f) aidx[b] = c0 + 3;
    if (f0.z > 0.5f) gidx[b] = c0;
    if (f1.y > 0.5f) gidx[b] = c0 + 1;
    if (f2.x > 0.5f) gidx[b] = c0 + 2;
    if (f2.w > 0.5f) gidx[b] = c0 + 3;
}

// ---------------- P2: transpose+compact Phi_w walls rows: PwT[n][c] = Phi_w[3c][n] ----------------
__global__ __launch_bounds__(256) void transpose_kernel(
    const float* __restrict__ Phi_w,  // (3072, 2048)
    _Float16* __restrict__ PwT)       // (2048, 1024)
{
    __shared__ float tile[32][33];
    const int tx = threadIdx.x & 31;
    const int ty = threadIdx.x >> 5;       // 0..7
    const int ci = blockIdx.y;             // 0..31  (c tile)
    const int ni = blockIdx.x;             // 0..63  (n tile)
    #pragma unroll
    for (int s = 0; s < 4; s++) {
        const int r = ty + 8 * s;
        tile[r][tx] = Phi_w[(size_t)(3 * (ci * 32 + r)) * DPHI + ni * 32 + tx];
    }
    __syncthreads();
    #pragma unroll
    for (int s = 0; s < 4; s++) {
        const int r = ty + 8 * s;
        PwT[(size_t)(ni * 32 + r) * KC + ci * 32 + tx] = (_Float16)tile[tx][r];
    }
}

// ---------------- GEMM: pre = W16 @ PwT^T + bias, stored f16 ----------------
// M=4096 N=2048 K=1024; 128x128 tile, BK=32, 256 threads, global_load_lds staging.
#define BM 128
#define BN 128

__global__ __launch_bounds__(256) void gemm_pre_kernel(
    const _Float16* __restrict__ A,    // (4096, 1024)
    const _Float16* __restrict__ Bt,   // (2048, 1024)  N-major
    const float* __restrict__ bias,    // (2048,)
    _Float16* __restrict__ pre)        // (4096, 2048)
{
    __shared__ _Float16 As2[4 * BM * 8];  // [kq][m][8]  8 KB
    __shared__ _Float16 Bs2[4 * BN * 8];  // [kq][n][8]  8 KB

    const int tid  = threadIdx.x;
    const int lane = tid & 63;
    const int wid  = tid >> 6;
    const int m0 = blockIdx.y * BM;
    const int n0 = blockIdx.x * BN;
    const int wm = (wid >> 1) * 64;
    const int wn = (wid & 1) * 64;
    const int lm = lane & 15;
    const int kq = lane >> 4;

    f32x4 acc[4][4] = {};

    const int sm  = tid & 127;   // staged row within tile
    const int sk0 = tid >> 7;    // 0..1
    const _Float16* Abase = A  + (size_t)(m0 + sm) * KC;
    const _Float16* Bbase = Bt + (size_t)(n0 + sm) * KC;

    for (int k0 = 0; k0 < KC; k0 += 32) {
        #pragma unroll
        for (int r2 = 0; r2 < 2; r2++) {
            const int kqs = sk0 + 2 * r2;   // chunk's kq
            load_lds16(Abase + k0 + kqs * 8, As2 + (tid + 256 * r2) * 8);
            load_lds16(Bbase + k0 + kqs * 8, Bs2 + (tid + 256 * r2) * 8);
        }
        __syncthreads();

        h8_t af[4], bf[4];
        #pragma unroll
        for (int mt = 0; mt < 4; mt++)
            af[mt] = *(const h8_t*)(As2 + (kq * BM + wm + mt * 16 + lm) * 8);
        #pragma unroll
        for (int nt = 0; nt < 4; nt++)
            bf[nt] = *(const h8_t*)(Bs2 + (kq * BN + wn + nt * 16 + lm) * 8);

        #pragma unroll
        for (int mt = 0; mt < 4; mt++)
            #pragma unroll
            for (int nt = 0; nt < 4; nt++)
                acc[mt][nt] = __builtin_amdgcn_mfma_f32_16x16x32_f16(
                    af[mt], bf[nt], acc[mt][nt], 0, 0, 0);
        __syncthreads();
    }

    #pragma unroll
    for (int nt = 0; nt < 4; nt++) {
        const int col = n0 + wn + nt * 16 + lm;
        const float bcol = bias[col];
        #pragma unroll
        for (int mt = 0; mt < 4; mt++) {
            #pragma unroll
            for (int r = 0; r < 4; r++) {
                const int row = m0 + wm + mt * 16 + kq * 4 + r;
                pre[(size_t)row * DPHI + col] = (_Float16)(acc[mt][nt][r] + bcol);
            }
        }
    }
}

// ---------------- B: one-hot row adds + sigmoid + vprop + gather + MLP ----------------
// Padded V layout: 34 rows x 40 floats; active cell (i,j) at [(i+1)*40 + 4 + j].
// Guards (row 0, row 33, col 3, col 36) stay zero = jnp.pad semantics.
__global__ __launch_bounds__(256) void vprop_head_kernel(
    const _Float16* __restrict__ pre,  // (4096, 2048)
    const float* __restrict__ Phi_w,   // (3072, 2048)
    const float* __restrict__ obs,     // (4096, 3072)
    const int* __restrict__ aidx,
    const int* __restrict__ gidx,
    const float* __restrict__ L1w,     // (36,16)
    const float* __restrict__ L1b,
    const float* __restrict__ L2w,     // (16,4)
    const float* __restrict__ L2b,
    float* __restrict__ out)           // (4096, 4)
{
    __shared__ __align__(16) float VB[2][34 * 40];
    __shared__ float sel[36], hbuf[16];

    const int b = blockIdx.x;
    const int tid = threadIdx.x;
    const int ai = aidx[b];
    const int gi = gidx[b];

    // zero both V buffers (guards + interior)
    for (int idx = tid; idx < 2 * 34 * 40; idx += 256)
        ((float*)VB)[idx] = 0.0f;

    // load 8 pre-activations (4 cells) + one-hot row contributions, sigmoid
    const h8_t ph = *(const h8_t*)(pre + (size_t)b * DPHI + 8 * tid);
    const float* rA = Phi_w + (size_t)(3 * ai + 1) * DPHI + 8 * tid;
    const float* rG = Phi_w + (size_t)(3 * gi + 2) * DPHI + 8 * tid;
    const float4 a0 = *(const float4*)(rA);
    const float4 a1 = *(const float4*)(rA + 4);
    const float4 g0 = *(const float4*)(rG);
    const float4 g1 = *(const float4*)(rG + 4);
    float v[8];
    v[0] = (float)ph[0] + a0.x + g0.x;  v[1] = (float)ph[1] + a0.y + g0.y;
    v[2] = (float)ph[2] + a0.z + g0.z;  v[3] = (float)ph[3] + a0.w + g0.w;
    v[4] = (float)ph[4] + a1.x + g1.x;  v[5] = (float)ph[5] + a1.y + g1.y;
    v[6] = (float)ph[6] + a1.z + g1.z;  v[7] = (float)ph[7] + a1.w + g1.w;

    float4 vR, pp, aR;  // r, p, r*(1-p) for this thread's 4 cells
    vR.x = sigmoidf(v[0]); pp.x = sigmoidf(v[1]);
    vR.y = sigmoidf(v[2]); pp.y = sigmoidf(v[3]);
    vR.z = sigmoidf(v[4]); pp.z = sigmoidf(v[5]);
    vR.w = sigmoidf(v[6]); pp.w = sigmoidf(v[7]);
    aR.x = vR.x * (1.0f - pp.x); aR.y = vR.y * (1.0f - pp.y);
    aR.z = vR.z * (1.0f - pp.z); aR.w = vR.w * (1.0f - pp.w);

    const int i = tid >> 3;            // row 0..31
    const int q = tid & 7;             // col quad
    const int rowoff = (i + 1) * 40 + 4 + 4 * q;

    __syncthreads();                   // zeroing done
    *(float4*)&VB[0][rowoff] = vR;
    __syncthreads();

    int cur = 0;
    for (int it = 0; it < KPROP; it++) {
        const float* Vold = VB[cur];
        float* Vnew = VB[1 - cur];
        const float4 up = *(const float4*)&Vold[rowoff - 40];
        const float4 dn = *(const float4*)&Vold[rowoff + 40];
        const float lf = Vold[rowoff - 1];
        const float rt = Vold[rowoff + 4];
        float4 nb;
        nb.x = fmaxf(fmaxf(up.x, dn.x), fmaxf(lf,   vR.y));
        nb.y = fmaxf(fmaxf(up.y, dn.y), fmaxf(vR.x, vR.z));
        nb.z = fmaxf(fmaxf(up.z, dn.z), fmaxf(vR.y, vR.w));
        nb.w = fmaxf(fmaxf(up.w, dn.w), fmaxf(vR.z, rt));
        vR.x = fmaxf(vR.x, aR.x + pp.x * nb.x);
        vR.y = fmaxf(vR.y, aR.y + pp.y * nb.y);
        vR.z = fmaxf(vR.z, aR.z + pp.z * nb.z);
        vR.w = fmaxf(vR.w, aR.w + pp.w * nb.w);
        *(float4*)&Vnew[rowoff] = vR;
        __syncthreads();
        cur ^= 1;
    }
    // final V is in VB[cur]

    const int pi = ai >> 5, pj = ai & 31;
    if (tid < 36) {
        const int cell = tid >> 2;   // 0..8
        const int ch = tid & 3;
        const int di = pi + cell / 3 - 1;
        const int dj = pj + cell % 3 - 1;
        float vv;
        if (ch == 3) {
            vv = VB[cur][(di + 1) * 40 + 4 + dj];  // guards give exact zero-pad
        } else {
            vv = 0.0f;
            if (di >= 0 && di < HH && dj >= 0 && dj < WW)
                vv = obs[(size_t)b * DIN + (di * WW + dj) * 3 + ch];
        }
        sel[tid] = vv;
    }
    __syncthreads();

    if (tid < 16) {
        float h = L1b[tid];
        #pragma unroll
        for (int k = 0; k < 36; k++) h += sel[k] * L1w[k * 16 + tid];
        hbuf[tid] = fmaxf(h, 0.0f);
    }
    __syncthreads();

    if (tid < 4) {
        float o = L2b[tid];
        #pragma unroll
        for (int t = 0; t < 16; t++) o += hbuf[t] * L2w[t * 4 + tid];
        out[(size_t)b * NACT + tid] = o;
    }
}

extern "C" void kernel_launch(void* const* d_in, const int* in_sizes, int n_in,
                              void* d_out, int out_size, void* d_ws, size_t ws_size,
                              hipStream_t stream) {
    const float* obs   = (const float*)d_in[0];
    const float* Phi_w = (const float*)d_in[1];
    const float* Phi_b = (const float*)d_in[2];
    const float* L1w   = (const float*)d_in[3];
    const float* L1b   = (const float*)d_in[4];
    const float* L2w   = (const float*)d_in[5];
    const float* L2b   = (const float*)d_in[6];
    float* out = (float*)d_out;

    char* ws = (char*)d_ws;
    _Float16* pre = (_Float16*)ws;                         // 16,777,216 B
    _Float16* W16 = (_Float16*)(ws + 16777216);            //  8,388,608 B
    _Float16* PwT = (_Float16*)(ws + 16777216 + 8388608);  //  4,194,304 B
    int* aidx = (int*)(ws + 29360128);                     //     16,384 B
    int* gidx = aidx + BATCH;                              //     16,384 B
    // total 29,392,896 B

    prep_kernel<<<BATCH, 256, 0, stream>>>(obs, W16, aidx, gidx);
    transpose_kernel<<<dim3(64, 32), 256, 0, stream>>>(Phi_w, PwT);
    gemm_pre_kernel<<<dim3(DPHI / BN, BATCH / BM), 256, 0, stream>>>(W16, PwT, Phi_b, pre);
    vprop_head_kernel<<<BATCH, 256, 0, stream>>>(pre, Phi_w, obs, aidx, gidx,
                                                 L1w, L1b, L2w, L2b, out);
}

// Round 3
// 178.457 us; speedup vs baseline: 1.6611x; 1.0211x over previous
//
#include <hip/hip_runtime.h>
#include <hip/hip_fp16.h>

#define BATCH 4096
#define HH 32
#define WW 32
#define KPROP 20
#define NACT 4
#define DIN 3072   // H*W*3
#define DPHI 2048  // 2*H*W
#define HWC 1024   // H*W
#define KC 1024    // compacted K (walls only)

typedef _Float16 h8_t __attribute__((ext_vector_type(8)));
typedef _Float16 h4_t __attribute__((ext_vector_type(4)));
typedef float f32x4 __attribute__((ext_vector_type(4)));

__device__ inline void load_lds16(const _Float16* g, _Float16* l) {
    __builtin_amdgcn_global_load_lds(
        (const __attribute__((address_space(1))) void*)g,
        (__attribute__((address_space(3))) void*)l, 16, 0, 0);
}

__device__ inline float sigmoidf(float x) { return 1.0f / (1.0f + __expf(-x)); }

// DPP lane-shift helpers: 16-lane DPP rows; bound_ctrl=1 -> 0 at row edges.
// With lane layout bi = lane&15 vertical, grid edges == DPP row edges (no masks).
__device__ inline float dpp_shr1(float x) {  // lane i <- lane i-1 (0 at i%16==0)
    return __int_as_float(__builtin_amdgcn_update_dpp(
        0, __float_as_int(x), 0x111, 0xF, 0xF, true));
}
__device__ inline float dpp_shl1(float x) {  // lane i <- lane i+1 (0 at i%16==15)
    return __int_as_float(__builtin_amdgcn_update_dpp(
        0, __float_as_int(x), 0x101, 0xF, 0xF, true));
}

// ---------------- P1: compact walls to f16, extract agent/goal indices ----------------
__global__ __launch_bounds__(256) void prep_kernel(
    const float* __restrict__ obs,  // (4096, 3072)
    _Float16* __restrict__ W16,     // (4096, 1024)
    int* __restrict__ aidx, int* __restrict__ gidx)
{
    const int t = blockIdx.x * 256 + threadIdx.x;
    const int b = t >> 8;
    const int c0 = (t & 255) * 4;
    const float* src = obs + (size_t)b * DIN + 3 * c0;
    const float4 f0 = *(const float4*)(src);
    const float4 f1 = *(const float4*)(src + 4);
    const float4 f2 = *(const float4*)(src + 8);
    h4_t w;
    w[0] = (_Float16)f0.x; w[1] = (_Float16)f0.w;
    w[2] = (_Float16)f1.z; w[3] = (_Float16)f2.y;
    *(h4_t*)(W16 + (size_t)b * KC + c0) = w;
    if (f0.y > 0.5f) aidx[b] = c0;
    if (f1.x > 0.5f) aidx[b] = c0 + 1;
    if (f1.w > 0.5f) aidx[b] = c0 + 2;
    if (f2.z > 0.5f) aidx[b] = c0 + 3;
    if (f0.z > 0.5f) gidx[b] = c0;
    if (f1.y > 0.5f) gidx[b] = c0 + 1;
    if (f2.x > 0.5f) gidx[b] = c0 + 2;
    if (f2.w > 0.5f) gidx[b] = c0 + 3;
}

// ------- P2: one pass over Phi_w: transposed f16 walls (PwT) + f16 agent/goal rows -------
__global__ __launch_bounds__(256) void wprep_kernel(
    const float* __restrict__ Phi_w,  // (3072, 2048)
    _Float16* __restrict__ PwT,       // (2048, 1024): PwT[n][c] = Phi_w[3c][n]
    _Float16* __restrict__ Pag)       // (2, 1024, 2048): [0][c]=row 3c+1, [1][c]=row 3c+2
{
    __shared__ float tile[32][33];
    const int tx = threadIdx.x & 31;
    const int ty = threadIdx.x >> 5;       // 0..7
    const int ci = blockIdx.y;             // 0..31
    const int ni = blockIdx.x;             // 0..63
    #pragma unroll
    for (int s = 0; s < 4; s++) {
        const int r = ty + 8 * s;
        const int c = ci * 32 + r;
        const int n = ni * 32 + tx;
        tile[r][tx] = Phi_w[(size_t)(3 * c) * DPHI + n];
        Pag[(size_t)c * DPHI + n]                      = (_Float16)Phi_w[(size_t)(3 * c + 1) * DPHI + n];
        Pag[(size_t)(HWC + c) * DPHI + n]              = (_Float16)Phi_w[(size_t)(3 * c + 2) * DPHI + n];
    }
    __syncthreads();
    #pragma unroll
    for (int s = 0; s < 4; s++) {
        const int r = ty + 8 * s;
        PwT[(size_t)(ni * 32 + r) * KC + ci * 32 + tx] = (_Float16)tile[tx][r];
    }
}

// ---------------- GEMM: pre = W16 @ PwT^T + bias, f16 out, LDS double-buffered ----------------
#define BM 128
#define BN 128

__device__ inline void stage_tile(const _Float16* Abase, const _Float16* Bbase, int k0,
                                  _Float16* As, _Float16* Bs, int tid) {
    const int sk0 = tid >> 7;
    #pragma unroll
    for (int r2 = 0; r2 < 2; r2++) {
        const int kqs = sk0 + 2 * r2;
        load_lds16(Abase + k0 + kqs * 8, As + (tid + 256 * r2) * 8);
        load_lds16(Bbase + k0 + kqs * 8, Bs + (tid + 256 * r2) * 8);
    }
}

__global__ __launch_bounds__(256) void gemm_pre_kernel(
    const _Float16* __restrict__ A,    // (4096, 1024)
    const _Float16* __restrict__ Bt,   // (2048, 1024)  N-major
    const float* __restrict__ bias,    // (2048,)
    _Float16* __restrict__ pre)        // (4096, 2048)
{
    __shared__ _Float16 As[2][4 * BM * 8];  // 2 x 8 KB
    __shared__ _Float16 Bs[2][4 * BN * 8];  // 2 x 8 KB

    const int tid  = threadIdx.x;
    const int lane = tid & 63;
    const int wid  = tid >> 6;
    const int m0 = blockIdx.y * BM;
    const int n0 = blockIdx.x * BN;
    const int wm = (wid >> 1) * 64;
    const int wn = (wid & 1) * 64;
    const int lm = lane & 15;
    const int kq = lane >> 4;

    f32x4 acc[4][4] = {};

    const int sm = tid & 127;
    const _Float16* Abase = A  + (size_t)(m0 + sm) * KC;
    const _Float16* Bbase = Bt + (size_t)(n0 + sm) * KC;

    stage_tile(Abase, Bbase, 0, As[0], Bs[0], tid);

    int cur = 0;
    for (int k0 = 0; k0 < KC; k0 += 32) {
        __syncthreads();   // drains this wave's vmcnt -> buf[cur] ready; buf[cur^1] fully consumed
        if (k0 + 32 < KC)
            stage_tile(Abase, Bbase, k0 + 32, As[cur ^ 1], Bs[cur ^ 1], tid);

        h8_t af[4], bf[4];
        #pragma unroll
        for (int mt = 0; mt < 4; mt++)
            af[mt] = *(const h8_t*)(As[cur] + (kq * BM + wm + mt * 16 + lm) * 8);
        #pragma unroll
        for (int nt = 0; nt < 4; nt++)
            bf[nt] = *(const h8_t*)(Bs[cur] + (kq * BN + wn + nt * 16 + lm) * 8);

        #pragma unroll
        for (int mt = 0; mt < 4; mt++)
            #pragma unroll
            for (int nt = 0; nt < 4; nt++)
                acc[mt][nt] = __builtin_amdgcn_mfma_f32_16x16x32_f16(
                    af[mt], bf[nt], acc[mt][nt], 0, 0, 0);
        cur ^= 1;
    }

    #pragma unroll
    for (int nt = 0; nt < 4; nt++) {
        const int col = n0 + wn + nt * 16 + lm;
        const float bcol = bias[col];
        #pragma unroll
        for (int mt = 0; mt < 4; mt++) {
            #pragma unroll
            for (int r = 0; r < 4; r++) {
                const int row = m0 + wm + mt * 16 + kq * 4 + r;
                pre[(size_t)row * DPHI + col] = (_Float16)(acc[mt][nt][r] + bcol);
            }
        }
    }
}

// ---------------- B: sigmoid + 20-step vprop entirely in registers + head MLP ----------------
// 1 wave per sample, 4 samples per block. Lane owns a 2-row x 8-col cell block:
//   bi = lane&15 -> rows {2bi, 2bi+1}; bj = lane>>4 -> cols {8bj..8bj+7}.
// Vertical halo: DPP lane+-1 (grid edge == DPP row edge -> bound_ctrl zero-pad).
// Horizontal halo: __shfl lane+-16 (2 values/side). No LDS, no barriers in the loop.
__global__ __launch_bounds__(256, 4) void vprop_head_kernel(
    const _Float16* __restrict__ pre,  // (4096, 2048)
    const _Float16* __restrict__ Pag,  // (2, 1024, 2048)
    const float* __restrict__ obs,     // (4096, 3072)
    const int* __restrict__ aidx,
    const int* __restrict__ gidx,
    const float* __restrict__ L1w,     // (36,16)
    const float* __restrict__ L1b,
    const float* __restrict__ L2w,     // (16,4)
    const float* __restrict__ L2b,
    float* __restrict__ out)           // (4096, 4)
{
    __shared__ __align__(16) float Vg[4][HWC];
    __shared__ float sel[4][36], hbuf[4][16];

    const int tid  = threadIdx.x;
    const int w    = tid >> 6;
    const int lane = tid & 63;
    const int b    = blockIdx.x * 4 + w;
    const int bi   = lane & 15;
    const int bj   = lane >> 4;
    const int ai = aidx[b];
    const int gi = gidx[b];

    const _Float16* pb = pre + (size_t)b * DPHI;
    const _Float16* ra = Pag + (size_t)ai * DPHI;
    const _Float16* rg = Pag + (size_t)(HWC + gi) * DPHI;

    float v[2][8], p[2][8], a[2][8];
    #pragma unroll
    for (int r = 0; r < 2; r++) {
        const int off = 64 * (2 * bi + r) + 16 * bj;
        const h8_t ph0 = *(const h8_t*)(pb + off), ph1 = *(const h8_t*)(pb + off + 8);
        const h8_t pa0 = *(const h8_t*)(ra + off), pa1 = *(const h8_t*)(ra + off + 8);
        const h8_t pg0 = *(const h8_t*)(rg + off), pg1 = *(const h8_t*)(rg + off + 8);
        #pragma unroll
        for (int c = 0; c < 4; c++) {
            const float rv = sigmoidf((float)ph0[2*c]   + (float)pa0[2*c]   + (float)pg0[2*c]);
            const float pv = sigmoidf((float)ph0[2*c+1] + (float)pa0[2*c+1] + (float)pg0[2*c+1]);
            v[r][c] = rv; p[r][c] = pv; a[r][c] = rv * (1.0f - pv);
            const float rv2 = sigmoidf((float)ph1[2*c]   + (float)pa1[2*c]   + (float)pg1[2*c]);
            const float pv2 = sigmoidf((float)ph1[2*c+1] + (float)pa1[2*c+1] + (float)pg1[2*c+1]);
            v[r][c+4] = rv2; p[r][c+4] = pv2; a[r][c+4] = rv2 * (1.0f - pv2);
        }
    }

    for (int it = 0; it < KPROP; it++) {
        float uh[8], dh[8], lh[2], rh[2];
        #pragma unroll
        for (int c = 0; c < 8; c++) {
            uh[c] = dpp_shr1(v[1][c]);   // bottom row of lane above (0 at top edge)
            dh[c] = dpp_shl1(v[0][c]);   // top row of lane below (0 at bottom edge)
        }
        #pragma unroll
        for (int r = 0; r < 2; r++) {
            lh[r] = __shfl(v[r][7], lane - 16);
            rh[r] = __shfl(v[r][0], lane + 16);
            if (bj == 0) lh[r] = 0.0f;
            if (bj == 3) rh[r] = 0.0f;
        }
        float nb[2][8];
        #pragma unroll
        for (int c = 0; c < 8; c++) {
            const float lf0 = (c == 0) ? lh[0] : v[0][c-1];
            const float rt0 = (c == 7) ? rh[0] : v[0][c+1];
            const float lf1 = (c == 0) ? lh[1] : v[1][c-1];
            const float rt1 = (c == 7) ? rh[1] : v[1][c+1];
            nb[0][c] = fmaxf(fmaxf(uh[c], v[1][c]), fmaxf(lf0, rt0));
            nb[1][c] = fmaxf(fmaxf(v[0][c], dh[c]), fmaxf(lf1, rt1));
        }
        #pragma unroll
        for (int r = 0; r < 2; r++)
            #pragma unroll
            for (int c = 0; c < 8; c++)
                v[r][c] = fmaxf(v[r][c], fmaf(p[r][c], nb[r][c], a[r][c]));
    }

    // dump V to LDS for the dynamic 3x3 gather
    #pragma unroll
    for (int r = 0; r < 2; r++) {
        float4 lo, hi;
        lo.x = v[r][0]; lo.y = v[r][1]; lo.z = v[r][2]; lo.w = v[r][3];
        hi.x = v[r][4]; hi.y = v[r][5]; hi.z = v[r][6]; hi.w = v[r][7];
        const int base = (2 * bi + r) * 32 + 8 * bj;
        *(float4*)&Vg[w][base]     = lo;
        *(float4*)&Vg[w][base + 4] = hi;
    }
    __syncthreads();

    const int pi = ai >> 5, pj = ai & 31;
    if (lane < 36) {
        const int cell = lane >> 2;   // 0..8
        const int ch = lane & 3;
        const int di = pi + cell / 3 - 1;
        const int dj = pj + cell % 3 - 1;
        float vv = 0.0f;
        if (di >= 0 && di < HH && dj >= 0 && dj < WW) {
            const int c = di * WW + dj;
            vv = (ch < 3) ? obs[(size_t)b * DIN + 3 * c + ch] : Vg[w][c];
        }
        sel[w][lane] = vv;
    }
    __syncthreads();

    if (lane < 16) {
        float h = L1b[lane];
        #pragma unroll
        for (int k = 0; k < 36; k++) h += sel[w][k] * L1w[k * 16 + lane];
        hbuf[w][lane] = fmaxf(h, 0.0f);
    }
    __syncthreads();

    if (lane < 4) {
        float o = L2b[lane];
        #pragma unroll
        for (int t = 0; t < 16; t++) o += hbuf[w][t] * L2w[t * 4 + lane];
        out[(size_t)b * NACT + lane] = o;
    }
}

extern "C" void kernel_launch(void* const* d_in, const int* in_sizes, int n_in,
                              void* d_out, int out_size, void* d_ws, size_t ws_size,
                              hipStream_t stream) {
    const float* obs   = (const float*)d_in[0];
    const float* Phi_w = (const float*)d_in[1];
    const float* Phi_b = (const float*)d_in[2];
    const float* L1w   = (const float*)d_in[3];
    const float* L1b   = (const float*)d_in[4];
    const float* L2w   = (const float*)d_in[5];
    const float* L2b   = (const float*)d_in[6];
    float* out = (float*)d_out;

    char* ws = (char*)d_ws;
    _Float16* pre = (_Float16*)ws;                  // 16,777,216 B
    _Float16* W16 = (_Float16*)(ws + 16777216);     //  8,388,608 B
    _Float16* PwT = (_Float16*)(ws + 25165824);     //  4,194,304 B
    _Float16* Pag = (_Float16*)(ws + 29360128);     //  8,388,608 B
    int* aidx = (int*)(ws + 37748736);              //     16,384 B
    int* gidx = aidx + BATCH;                       //     16,384 B

    prep_kernel<<<BATCH, 256, 0, stream>>>(obs, W16, aidx, gidx);
    wprep_kernel<<<dim3(64, 32), 256, 0, stream>>>(Phi_w, PwT, Pag);
    gemm_pre_kernel<<<dim3(DPHI / BN, BATCH / BM), 256, 0, stream>>>(W16, PwT, Phi_b, pre);
    vprop_head_kernel<<<BATCH / 4, 256, 0, stream>>>(pre, Pag, obs, aidx, gidx,
                                                     L1w, L1b, L2w, L2b, out);
}